// Round 15
// baseline (300.284 us; speedup 1.0000x reference)
//
#include <hip/hip_runtime.h>
#include <math.h>

namespace {
constexpr int   BS_   = 64;
constexpr int   D_    = 768;
constexpr int   NVL_  = 192;            // 3*BS rows of vl_embeddings
constexpr int   NQ_   = 128;            // query rows (vl[64:])
constexpr int   CAP_  = 131072;
constexpr int   NCOL_ = NVL_ + CAP_;    // 131264 (the PRE dimension)
constexpr float THR_  = 0.5f;
constexpr float EPS_  = 1e-8f;

// workspace float offsets
constexpr int WS_QN   = 0;    // 128 query norms
constexpr int WS_SL   = 128;  // 1   global label sum
constexpr int WS_MN   = 160;  // 128 per-query min(sim_m)
constexpr int WS_MX   = 288;  // 128 per-query max(sim_m)
constexpr int WS_SS   = 416;  // 128 per-query sum(sim_m + 1)
constexpr int WS_SSL  = 544;  // 128 per-query sum((sim_m + 1)*label)
constexpr int WS_S0   = 672;  // 128 per-query sum(sim where selected)
constexpr int WS_CNT  = 800;  // 128 per-query count(selected)
constexpr int WS_ZERO = 1024; // 768 zero floats (safe OOB source)
constexpr int WS_QBF  = 2048; // 49152 floats: q bf16, 24 chunks of 8192 B (swizzled LDS image)

constexpr int TM    = 128;    // pre-rows per block
constexpr int NSTEP = 12;     // 64-k steps
}

using bf16x8 = __attribute__((ext_vector_type(8))) short;
using f32x4  = __attribute__((ext_vector_type(4))) float;

__device__ inline void atomicMinF(float* addr, float v) {
    if (v >= 0.f) atomicMin((int*)addr, __float_as_int(v));
    else          atomicMax((unsigned int*)addr, __float_as_uint(v));
}
__device__ inline void atomicMaxF(float* addr, float v) {
    if (v >= 0.f) atomicMax((int*)addr, __float_as_int(v));
    else          atomicMin((unsigned int*)addr, __float_as_uint(v));
}
// pack two f32 -> two bf16 (RNE) in one u32 (integer path, used in prep)
__device__ inline unsigned pk2bf(float a, float b) {
    unsigned ua = __float_as_uint(a), ub = __float_as_uint(b);
    ua += 0x7fffu + ((ua >> 16) & 1u);
    ub += 0x7fffu + ((ub >> 16) & 1u);
    return (ua >> 16) | (ub & 0xffff0000u);
}
// single-instruction pack; rounding differences vs pk2bf perturb cos <=2^-15.
__device__ inline unsigned cvtpk(float a, float b) {
    unsigned r;
    asm("v_cvt_pk_bf16_f32 %0, %1, %2" : "=v"(r) : "v"(a), "v"(b));
    return r;
}

// ---------------- kernel 0: init accumulators + zero pad buffer ----------------
__global__ void lpe_init(float* ws) {
    int t = threadIdx.x;
    if (t < NQ_) {
        ws[WS_MN + t]  = INFINITY;
        ws[WS_MX + t]  = -INFINITY;
        ws[WS_SS + t]  = 0.f;
        ws[WS_SSL + t] = 0.f;
        ws[WS_S0 + t]  = 0.f;
        ws[WS_CNT + t] = 0.f;
    }
    if (t == 0) ws[WS_SL] = 0.f;
    for (int i = t; i < D_; i += 256) ws[WS_ZERO + i] = 0.f;
}

// ---------------- kernel 1: query norms + q bf16 image + global label sum ----------------
__global__ void lpe_prep(const float* __restrict__ vl,
                         const float* __restrict__ itm,
                         const float* __restrict__ expl,
                         float* ws) {
    __shared__ float red[256];
    int b = blockIdx.x, t = threadIdx.x;
    if (b < NQ_) {
        const float* row = vl + (size_t)(BS_ + b) * D_;
        float s = 0.f;
        for (int k = t; k < D_; k += 256) { float v = row[k]; s += v * v; }
        red[t] = s; __syncthreads();
        for (int o = 128; o > 0; o >>= 1) { if (t < o) red[t] += red[t + o]; __syncthreads(); }
        if (t == 0) ws[WS_QN + b] = sqrtf(red[0]);
        // swizzled bf16 image: chunk c (8192 B) = [row][64 B], byte = (kk*2) ^ ((row>>1 & 3)<<4)
        unsigned* qbf = (unsigned*)(ws + WS_QBF);
        const int sw = ((b >> 1) & 3) << 4;
        for (int k2 = t; k2 < 384; k2 += 256) {
            const int k = 2 * k2, chunk = k >> 5, kk = k & 31;
            const unsigned val = pk2bf(row[k], row[k + 1]);
            const int byte = chunk * 8192 + b * 64 + (((kk * 2) ^ sw) & 63);
            qbf[byte >> 2] = val;
        }
    } else {
        int idx = (b - NQ_) * 256 + t;
        float s = 0.f;
        for (int j = idx; j < NCOL_; j += 256 * 256)
            s += (j < NVL_) ? itm[j] : expl[j - NVL_];
        red[t] = s; __syncthreads();
        for (int o = 128; o > 0; o >>= 1) { if (t < o) red[t] += red[t + o]; __syncthreads(); }
        if (t == 0) atomicAdd(ws + WS_SL, red[0]);
    }
}

// ---------------- kernel 2: 64-k steps, 12 barriers, counted vmcnt(8) ----------------
// M = pre rows (128/block), N = 128 queries, K = 768, 12 steps of 64-k.
__global__ __launch_bounds__(256, 3) void lpe_main(
        const float* __restrict__ vl, const float* __restrict__ score,
        const float* __restrict__ itm, const float* __restrict__ queue,
        const float* __restrict__ expl, const float* __restrict__ W,
        const float* __restrict__ bvec, float* ws) {
    __shared__ __align__(16) short Bs[4][NQ_][32];     // two pairs of 32-k chunks, 32 KB
    __shared__ __align__(16) float u_l[D_];            // u = W[:,1]-W[:,0], 3 KB
    __shared__ float rn_s[TM], rsc_s[TM], lab_s[TM];
    __shared__ float qn_sh[NQ_], qsc_sh[NQ_];
    __shared__ float qmn[NQ_], qmx[NQ_], qss[NQ_], qssl[NQ_], qs0[NQ_], qcnt[NQ_];

    const int t    = threadIdx.x;
    const int lane = t & 63;
    const int wv   = t >> 6;        // wave 0..3 computes rows wv*32..+31
    const int fr   = lane & 15;
    const int fq   = lane >> 4;
    const int row0 = blockIdx.x * TM;

    if (t < NQ_) {
        qn_sh[t]  = ws[WS_QN + t];
        qsc_sh[t] = score[BS_ + t];
        qmn[t] = INFINITY; qmx[t] = -INFINITY;
        qss[t] = 0.f; qssl[t] = 0.f; qs0[t] = 0.f; qcnt[t] = 0.f;
        int rg = row0 + t;
        lab_s[t] = (rg < NCOL_) ? ((rg < NVL_) ? itm[rg] : expl[rg - NVL_]) : 0.f;
    }
    for (int i = t; i < D_; i += 256) u_l[i] = W[2 * i + 1] - W[2 * i];
    const float bu = bvec[1] - bvec[0];
    const float* zb = ws + WS_ZERO;

    // per-lane A row pointers (frag: row = wv*32 + m*16 + fr, k-slice = fq*8)
    const float* ap[2];
#pragma unroll
    for (int m = 0; m < 2; ++m) {
        const int rg = row0 + wv * 32 + m * 16 + fr;
        const float* base = (rg < NVL_)  ? (vl + (size_t)rg * D_)
                          : (rg < NCOL_) ? (queue + (size_t)(rg - NVL_) * D_)
                                         : zb;
        ap[m] = base + fq * 8;
    }
    const char* qbf = (const char*)(ws + WS_QBF);

    float ssr[2] = {0.f, 0.f}, zr[2] = {0.f, 0.f};
    f32x4 acc[2][8];
#pragma unroll
    for (int m = 0; m < 2; ++m)
#pragma unroll
        for (int n = 0; n < 8; ++n) acc[m][n] = (f32x4){0.f, 0.f, 0.f, 0.f};

    float4 aA[2][4], aB[2][4];   // [m][kk*2+h] one 64-k step each (static indexing)

    // block-cooperative staging of 32-k chunk SRCC into buffer DB (2 insts/wave)
#define STAGE_B(SRCC, DB) {                                                    \
    char* lb_ = (char*)&Bs[0][0][0] + (size_t)(DB) * 8192 + wv * 2048;         \
    const char* src_ = qbf + (size_t)(SRCC) * 8192 + wv * 2048 + lane * 16;    \
    _Pragma("unroll")                                                          \
    for (int i_ = 0; i_ < 2; ++i_)                                             \
        __builtin_amdgcn_global_load_lds(                                      \
            (const __attribute__((address_space(1))) void*)(src_ + i_ * 1024), \
            (__attribute__((address_space(3))) void*)(lb_ + i_ * 1024),        \
            16, 0, 0); }

    // 8 vmem insts: 64-k step S, both 32-k halves
#define LOAD_A2(DST, S) {                                                      \
    _Pragma("unroll")                                                          \
    for (int m_ = 0; m_ < 2; ++m_) {                                           \
        const float* p_ = ap[m_] + (S) * 64;                                   \
        DST[m_][0] = *(const float4*)(p_);                                     \
        DST[m_][1] = *(const float4*)(p_ + 4);                                 \
        DST[m_][2] = *(const float4*)(p_ + 32);                                \
        DST[m_][3] = *(const float4*)(p_ + 36);                                \
    } }

    // one 64-k step: two 32-k halves from buffer pair PB, 32 MFMA, fp32 stats
#define COMPUTE2(S, AR, PB) {                                                  \
    _Pragma("unroll")                                                          \
    for (int kk_ = 0; kk_ < 2; ++kk_) {                                        \
        bf16x8 af_[2];                                                         \
        const float* up_ = &u_l[(S) * 64 + kk_ * 32 + fq * 8];                 \
        const float4 u0_ = *(const float4*)(up_);                              \
        const float4 u1_ = *(const float4*)(up_ + 4);                          \
        _Pragma("unroll")                                                      \
        for (int m_ = 0; m_ < 2; ++m_) {                                       \
            const float4 v0_ = AR[m_][kk_ * 2];                                \
            const float4 v1_ = AR[m_][kk_ * 2 + 1];                            \
            ssr[m_] += v0_.x*v0_.x + v0_.y*v0_.y + v0_.z*v0_.z + v0_.w*v0_.w   \
                     + v1_.x*v1_.x + v1_.y*v1_.y + v1_.z*v1_.z + v1_.w*v1_.w;  \
            zr[m_]  += v0_.x*u0_.x + v0_.y*u0_.y + v0_.z*u0_.z + v0_.w*u0_.w   \
                     + v1_.x*u1_.x + v1_.y*u1_.y + v1_.z*u1_.z + v1_.w*u1_.w;  \
            union { unsigned u[4]; bf16x8 v; } cv_;                            \
            cv_.u[0] = cvtpk(v0_.x, v0_.y); cv_.u[1] = cvtpk(v0_.z, v0_.w);    \
            cv_.u[2] = cvtpk(v1_.x, v1_.y); cv_.u[3] = cvtpk(v1_.z, v1_.w);    \
            af_[m_] = cv_.v;                                                   \
        }                                                                      \
        const char* bb_ = (const char*)&Bs[0][0][0] + (size_t)((PB) + kk_) * 8192; \
        _Pragma("unroll")                                                      \
        for (int n_ = 0; n_ < 8; ++n_) {                                       \
            const int rb_ = n_ * 16 + fr;                                      \
            bf16x8 bv_ = *(const bf16x8*)(bb_ + rb_ * 64 + 16 * (fq ^ ((rb_ >> 1) & 3))); \
            acc[0][n_] = __builtin_amdgcn_mfma_f32_16x16x32_bf16(af_[0], bv_, acc[0][n_], 0, 0, 0); \
            acc[1][n_] = __builtin_amdgcn_mfma_f32_16x16x32_bf16(af_[1], bv_, acc[1][n_], 0, 0, 0); \
        }                                                                      \
    } }

    // prologue: B(0) chunks 0,1 -> bufs 0,1; A(0),A(1); full drain publishes all
    STAGE_B(0, 0);
    STAGE_B(1, 1);
    LOAD_A2(aA, 0);
    LOAD_A2(aB, 1);
    __syncthreads();

    // main loop: per step = COMPUTE2; stage B(S+1) into opposite pair;
    // prefetch A(S+2); vmcnt(8) keeps newest 8 A outstanding, drains B; barrier.
#pragma unroll 1
    for (int S = 0; S < NSTEP; S += 2) {
        const int k2 = 2 * S + 2 <= 23 ? 2 * S + 2 : 23;
        const int k3 = 2 * S + 3 <= 23 ? 2 * S + 3 : 23;
        const int k4 = 2 * S + 4 <= 23 ? 2 * S + 4 : 23;
        const int k5 = 2 * S + 5 <= 23 ? 2 * S + 5 : 23;
        const int s2 = S + 2 <= 11 ? S + 2 : 11;
        const int s3 = S + 3 <= 11 ? S + 3 : 11;
        COMPUTE2(S, aA, 0);           // bufs 0,1
        STAGE_B(k2, 2);
        STAGE_B(k3, 3);
        LOAD_A2(aA, s2);
        asm volatile("s_waitcnt vmcnt(8)" ::: "memory");
        __builtin_amdgcn_s_barrier();
        asm volatile("" ::: "memory");
        COMPUTE2(S + 1, aB, 2);       // bufs 2,3
        STAGE_B(k4, 0);
        STAGE_B(k5, 1);
        LOAD_A2(aB, s3);
        asm volatile("s_waitcnt vmcnt(8)" ::: "memory");
        __builtin_amdgcn_s_barrier();
        asm volatile("" ::: "memory");
    }
#undef STAGE_B
#undef LOAD_A2
#undef COMPUTE2

    // per-pre-row stats: reduce over the 4 fq lanes sharing a row (same wave)
#pragma unroll
    for (int m = 0; m < 2; ++m) {
        ssr[m] += __shfl_xor(ssr[m], 16); ssr[m] += __shfl_xor(ssr[m], 32);
        zr[m]  += __shfl_xor(zr[m], 16);  zr[m]  += __shfl_xor(zr[m], 32);
        if (fq == 0) {
            const int r  = wv * 32 + m * 16 + fr;
            const int rg = row0 + r;
            rn_s[r] = sqrtf(ssr[m]);
            float sc;
            if (rg < NVL_) sc = score[rg];
            else { float z = zr[m] + bu; sc = 1.f / (1.f + expf(-z)); }
            rsc_s[r] = sc;
        }
    }

    // epilogue: per-query online reductions over this block's TM pre-rows
    // (rn_s/rsc_s own-wave-written; lab_s/qn_sh/qsc_sh published by prologue barrier)
#pragma unroll
    for (int n = 0; n < 8; ++n) {
        const int   c   = n * 16 + fr;
        const float qn  = qn_sh[c];
        const float qsc = qsc_sh[c];
        float mn = INFINITY, mx = -INFINITY, sss = 0.f, ssl = 0.f, s0 = 0.f, cnt = 0.f;
#pragma unroll
        for (int m = 0; m < 2; ++m) {
#pragma unroll
            for (int j = 0; j < 4; ++j) {
                const int r  = wv * 32 + m * 16 + fq * 4 + j;   // C row = pre row
                const int rg = row0 + r;
                const float d    = acc[m][n][j];
                const float cosv = d / fmaxf(rn_s[r] * qn, EPS_);
                float dd = rsc_s[r] - qsc; dd *= dd;
                const float sim   = cosv * (1.f - dd);
                const bool  sel   = (cosv >= THR_);
                const float sim_m = sel ? sim : -1.f;
                const bool  valid = (rg < NCOL_);
                mn = fminf(mn, valid ? sim_m : INFINITY);
                mx = fmaxf(mx, valid ? sim_m : -INFINITY);
                sss += sim_m + 1.f;                 // OOB rows: cos=0 -> exactly 0
                ssl += (sim_m + 1.f) * lab_s[r];
                if (sel) { s0 += sim; cnt += 1.f; }
            }
        }
        mn  = fminf(mn, __shfl_xor(mn, 16)); mn  = fminf(mn, __shfl_xor(mn, 32));
        mx  = fmaxf(mx, __shfl_xor(mx, 16)); mx  = fmaxf(mx, __shfl_xor(mx, 32));
        sss += __shfl_xor(sss, 16); sss += __shfl_xor(sss, 32);
        ssl += __shfl_xor(ssl, 16); ssl += __shfl_xor(ssl, 32);
        s0  += __shfl_xor(s0, 16);  s0  += __shfl_xor(s0, 32);
        cnt += __shfl_xor(cnt, 16); cnt += __shfl_xor(cnt, 32);
        if (fq == 0) {
            atomicMinF(&qmn[c], mn);
            atomicMaxF(&qmx[c], mx);
            atomicAdd(&qss[c],  sss);
            atomicAdd(&qssl[c], ssl);
            atomicAdd(&qs0[c],  s0);
            atomicAdd(&qcnt[c], cnt);
        }
    }
    __syncthreads();
    if (t < NQ_) {
        atomicMinF(ws + WS_MN + t, qmn[t]);
        atomicMaxF(ws + WS_MX + t, qmx[t]);
        atomicAdd(ws + WS_SS + t,  qss[t]);
        atomicAdd(ws + WS_SSL + t, qssl[t]);
        atomicAdd(ws + WS_S0 + t,  qs0[t]);
        atomicAdd(ws + WS_CNT + t, qcnt[t]);
    }
}

// ---------------- kernel 3: finalize outputs ----------------
__global__ void lpe_final(float* out, const float* ws) {
    int t = threadIdx.x;
    if (t < BS_) {
        out[t] = 1.f;            // exp_itm_label[:64]
        out[192 + t] = 1.f;      // exp_wo_alter_label[:64]
        out[385 + t] = 0.f;      // weights[:64]
    }
    if (t == 0) out[384] = 1.0f; // gamma = 131264/131264
    if (t >= BS_ && t < NVL_) {
        int i = t - BS_;
        float mn   = ws[WS_MN + i],  mx   = ws[WS_MX + i];
        float ssP  = ws[WS_SS + i],  sslP = ws[WS_SSL + i];
        float s0   = ws[WS_S0 + i],  cnt  = ws[WS_CNT + i];
        float Sl   = ws[WS_SL];
        float denomA = mx - mn + 1e-8f;
        float shift  = mn + 1.f;            // == 0 when min is the -1 sentinel
        float sumd = (ssP - (float)NCOL_ * shift) / denomA;
        float num  = (sslP - shift * Sl) / denomA;
        float wo   = num / (sumd + 1e-8f);
        float alt  = fmaxf(wo, 0.f);
        float w    = (cnt != 0.f) ? s0 / fmaxf(cnt, 1.f) : 0.f;
        float wt   = fmaxf(w - THR_, 0.f) / (1.f - THR_);
        out[BS_ + i] = alt;          // exp_itm_label[64:]
        out[192 + BS_ + i] = wo;     // exp_wo_alter_label[64:]
        out[385 + BS_ + i] = wt;     // weights[64:]
    }
}

extern "C" void kernel_launch(void* const* d_in, const int* in_sizes, int n_in,
                              void* d_out, int out_size, void* d_ws, size_t ws_size,
                              hipStream_t stream) {
    const float* vl    = (const float*)d_in[0];
    const float* score = (const float*)d_in[1];
    const float* itm   = (const float*)d_in[2];
    const float* queue = (const float*)d_in[3];
    const float* expl  = (const float*)d_in[4];
    const float* W     = (const float*)d_in[5];
    const float* b     = (const float*)d_in[6];
    float* out = (float*)d_out;
    float* ws  = (float*)d_ws;

    lpe_init<<<1, 256, 0, stream>>>(ws);
    lpe_prep<<<NQ_ + 256, 256, 0, stream>>>(vl, itm, expl, ws);
    const int nblk = (NCOL_ + TM - 1) / TM;   // 1026
    lpe_main<<<nblk, 256, 0, stream>>>(vl, score, itm, queue, expl, W, b, ws);
    lpe_final<<<1, 256, 0, stream>>>(out, ws);
}

// Round 16
// 123.969 us; speedup vs baseline: 2.4223x; 2.4223x over previous
//
#include <hip/hip_runtime.h>
#include <math.h>

namespace {
constexpr int   BS_   = 64;
constexpr int   D_    = 768;
constexpr int   NVL_  = 192;            // 3*BS rows of vl_embeddings
constexpr int   NQ_   = 128;            // query rows (vl[64:])
constexpr int   CAP_  = 131072;
constexpr int   NCOL_ = NVL_ + CAP_;    // 131264 (the PRE dimension)
constexpr float THR_  = 0.5f;
constexpr float EPS_  = 1e-8f;

// workspace float offsets
constexpr int WS_QN   = 0;    // 128 query norms
constexpr int WS_SL   = 128;  // 1   global label sum
constexpr int WS_MN   = 160;  // 128 per-query min(sim_m)
constexpr int WS_MX   = 288;  // 128 per-query max(sim_m)
constexpr int WS_SS   = 416;  // 128 per-query sum(sim_m + 1)
constexpr int WS_SSL  = 544;  // 128 per-query sum((sim_m + 1)*label)
constexpr int WS_S0   = 672;  // 128 per-query sum(sim where selected)
constexpr int WS_CNT  = 800;  // 128 per-query count(selected)
constexpr int WS_ZERO = 1024; // 768 zero floats (safe OOB source)
constexpr int WS_QBF  = 2048; // 49152 floats: q bf16, 24 chunks of 8192 B (swizzled LDS image)

constexpr int TM    = 128;    // pre-rows per block
constexpr int BK    = 32;     // k per half-step
constexpr int NSTEP = D_ / BK;   // 24
}

using bf16x8 = __attribute__((ext_vector_type(8))) short;
using f32x4  = __attribute__((ext_vector_type(4))) float;

__device__ inline void atomicMinF(float* addr, float v) {
    if (v >= 0.f) atomicMin((int*)addr, __float_as_int(v));
    else          atomicMax((unsigned int*)addr, __float_as_uint(v));
}
__device__ inline void atomicMaxF(float* addr, float v) {
    if (v >= 0.f) atomicMax((int*)addr, __float_as_int(v));
    else          atomicMin((unsigned int*)addr, __float_as_uint(v));
}
// pack two f32 -> two bf16 (RNE) in one u32 (integer path, used in prep)
__device__ inline unsigned pk2bf(float a, float b) {
    unsigned ua = __float_as_uint(a), ub = __float_as_uint(b);
    ua += 0x7fffu + ((ua >> 16) & 1u);
    ub += 0x7fffu + ((ub >> 16) & 1u);
    return (ua >> 16) | (ub & 0xffff0000u);
}
// single-instruction pack; rounding differences vs pk2bf perturb cos <=2^-15.
__device__ inline unsigned cvtpk(float a, float b) {
    unsigned r;
    asm("v_cvt_pk_bf16_f32 %0, %1, %2" : "=v"(r) : "v"(a), "v"(b));
    return r;
}

// ---------------- kernel 0: init accumulators + zero pad buffer ----------------
__global__ void lpe_init(float* ws) {
    int t = threadIdx.x;
    if (t < NQ_) {
        ws[WS_MN + t]  = INFINITY;
        ws[WS_MX + t]  = -INFINITY;
        ws[WS_SS + t]  = 0.f;
        ws[WS_SSL + t] = 0.f;
        ws[WS_S0 + t]  = 0.f;
        ws[WS_CNT + t] = 0.f;
    }
    if (t == 0) ws[WS_SL] = 0.f;
    for (int i = t; i < D_; i += 256) ws[WS_ZERO + i] = 0.f;
}

// ---------------- kernel 1: query norms + q bf16 image + global label sum ----------------
__global__ void lpe_prep(const float* __restrict__ vl,
                         const float* __restrict__ itm,
                         const float* __restrict__ expl,
                         float* ws) {
    __shared__ float red[256];
    int b = blockIdx.x, t = threadIdx.x;
    if (b < NQ_) {
        const float* row = vl + (size_t)(BS_ + b) * D_;
        float s = 0.f;
        for (int k = t; k < D_; k += 256) { float v = row[k]; s += v * v; }
        red[t] = s; __syncthreads();
        for (int o = 128; o > 0; o >>= 1) { if (t < o) red[t] += red[t + o]; __syncthreads(); }
        if (t == 0) ws[WS_QN + b] = sqrtf(red[0]);
        // swizzled bf16 image: chunk c (8192 B) = [row][64 B], byte = (kk*2) ^ ((row>>1 & 3)<<4)
        unsigned* qbf = (unsigned*)(ws + WS_QBF);
        const int sw = ((b >> 1) & 3) << 4;
        for (int k2 = t; k2 < 384; k2 += 256) {
            const int k = 2 * k2, chunk = k >> 5, kk = k & 31;
            const unsigned val = pk2bf(row[k], row[k + 1]);
            const int byte = chunk * 8192 + b * 64 + (((kk * 2) ^ sw) & 63);
            qbf[byte >> 2] = val;
        }
    } else {
        int idx = (b - NQ_) * 256 + t;
        float s = 0.f;
        for (int j = idx; j < NCOL_; j += 256 * 256)
            s += (j < NVL_) ? itm[j] : expl[j - NVL_];
        red[t] = s; __syncthreads();
        for (int o = 128; o > 0; o >>= 1) { if (t < o) red[t] += red[t + o]; __syncthreads(); }
        if (t == 0) atomicAdd(ws + WS_SL, red[0]);
    }
}

// ---------------- kernel 2: 12 barriers (1 per 64-k), r11 register pressure ----------
// M = pre rows (128/block), N = 128 queries, K = 768, BK = 32.
__global__ __launch_bounds__(256, 3) void lpe_main(
        const float* __restrict__ vl, const float* __restrict__ score,
        const float* __restrict__ itm, const float* __restrict__ queue,
        const float* __restrict__ expl, const float* __restrict__ W,
        const float* __restrict__ bvec, float* ws) {
    __shared__ __align__(16) short Bs[4][NQ_][BK];     // 4-chunk B rotation, 32 KB
    __shared__ __align__(16) float u_l[D_];            // u = W[:,1]-W[:,0], 3 KB
    __shared__ float rn_s[TM], rsc_s[TM], lab_s[TM];
    __shared__ float qn_sh[NQ_], qsc_sh[NQ_];
    __shared__ float qmn[NQ_], qmx[NQ_], qss[NQ_], qssl[NQ_], qs0[NQ_], qcnt[NQ_];

    const int t    = threadIdx.x;
    const int lane = t & 63;
    const int wv   = t >> 6;        // wave 0..3 computes rows wv*32..+31
    const int fr   = lane & 15;
    const int fq   = lane >> 4;
    const int row0 = blockIdx.x * TM;

    if (t < NQ_) {
        qn_sh[t]  = ws[WS_QN + t];
        qsc_sh[t] = score[BS_ + t];
        qmn[t] = INFINITY; qmx[t] = -INFINITY;
        qss[t] = 0.f; qssl[t] = 0.f; qs0[t] = 0.f; qcnt[t] = 0.f;
        int rg = row0 + t;
        lab_s[t] = (rg < NCOL_) ? ((rg < NVL_) ? itm[rg] : expl[rg - NVL_]) : 0.f;
    }
    for (int i = t; i < D_; i += 256) u_l[i] = W[2 * i + 1] - W[2 * i];
    const float bu = bvec[1] - bvec[0];
    const float* zb = ws + WS_ZERO;

    // per-lane A row pointers (frag: row = wv*32 + m*16 + fr, k-slice = fq*8)
    const float* ap[2];
#pragma unroll
    for (int m = 0; m < 2; ++m) {
        const int rg = row0 + wv * 32 + m * 16 + fr;
        const float* base = (rg < NVL_)  ? (vl + (size_t)rg * D_)
                          : (rg < NCOL_) ? (queue + (size_t)(rg - NVL_) * D_)
                                         : zb;
        ap[m] = base + fq * 8;
    }
    const char* qbf = (const char*)(ws + WS_QBF);

    float ssr[2] = {0.f, 0.f}, zr[2] = {0.f, 0.f};
    f32x4 acc[2][8];
#pragma unroll
    for (int m = 0; m < 2; ++m)
#pragma unroll
        for (int n = 0; n < 8; ++n) acc[m][n] = (f32x4){0.f, 0.f, 0.f, 0.f};

    float4 aA[2][2], aB[2][2];   // [m][half] A prefetch slots (static indexing only)

    // block-cooperative B staging: wave wv covers 2 KB of the 8 KB chunk (2 insts)
#define STAGE_B(SRCC, DB) {                                                    \
    char* lb_ = (char*)&Bs[0][0][0] + (size_t)(DB) * 8192 + wv * 2048;         \
    const char* src_ = qbf + (size_t)(SRCC) * 8192 + wv * 2048 + lane * 16;    \
    _Pragma("unroll")                                                          \
    for (int i_ = 0; i_ < 2; ++i_)                                             \
        __builtin_amdgcn_global_load_lds(                                      \
            (const __attribute__((address_space(1))) void*)(src_ + i_ * 1024), \
            (__attribute__((address_space(3))) void*)(lb_ + i_ * 1024),        \
            16, 0, 0); }

    // 4 vmem insts
#define LOAD_A(DST, S) {                                                       \
    _Pragma("unroll")                                                          \
    for (int m_ = 0; m_ < 2; ++m_) {                                           \
        const float* p_ = ap[m_] + (S) * BK;                                   \
        DST[m_][0] = *(const float4*)(p_);                                     \
        DST[m_][1] = *(const float4*)(p_ + 4);                                 \
    } }

#define COMPUTE(SB, AR, BUF) {                                                 \
    bf16x8 af_[2];                                                             \
    const float* up_ = &u_l[(SB) * 32 + fq * 8];                               \
    const float4 u0_ = *(const float4*)(up_);                                  \
    const float4 u1_ = *(const float4*)(up_ + 4);                              \
    _Pragma("unroll")                                                          \
    for (int m_ = 0; m_ < 2; ++m_) {                                           \
        const float4 v0_ = AR[m_][0];                                          \
        const float4 v1_ = AR[m_][1];                                          \
        ssr[m_] += v0_.x*v0_.x + v0_.y*v0_.y + v0_.z*v0_.z + v0_.w*v0_.w       \
                 + v1_.x*v1_.x + v1_.y*v1_.y + v1_.z*v1_.z + v1_.w*v1_.w;      \
        zr[m_]  += v0_.x*u0_.x + v0_.y*u0_.y + v0_.z*u0_.z + v0_.w*u0_.w       \
                 + v1_.x*u1_.x + v1_.y*u1_.y + v1_.z*u1_.z + v1_.w*u1_.w;      \
        union { unsigned u[4]; bf16x8 v; } cv_;                                \
        cv_.u[0] = cvtpk(v0_.x, v0_.y); cv_.u[1] = cvtpk(v0_.z, v0_.w);        \
        cv_.u[2] = cvtpk(v1_.x, v1_.y); cv_.u[3] = cvtpk(v1_.z, v1_.w);        \
        af_[m_] = cv_.v;                                                       \
    }                                                                          \
    const char* bb_ = (const char*)&Bs[0][0][0] + (size_t)(BUF) * 8192;        \
    _Pragma("unroll")                                                          \
    for (int n_ = 0; n_ < 8; ++n_) {                                           \
        const int rb_ = n_ * 16 + fr;                                          \
        bf16x8 bv_ = *(const bf16x8*)(bb_ + rb_ * 64 + 16 * (fq ^ ((rb_ >> 1) & 3))); \
        acc[0][n_] = __builtin_amdgcn_mfma_f32_16x16x32_bf16(af_[0], bv_, acc[0][n_], 0, 0, 0); \
        acc[1][n_] = __builtin_amdgcn_mfma_f32_16x16x32_bf16(af_[1], bv_, acc[1][n_], 0, 0, 0); \
    } }

    // prologue: chunks 0,1 -> bufs 0,1; A(0)->aA, A(1)->aB; full drain publishes all
    STAGE_B(0, 0);
    STAGE_B(1, 1);
    LOAD_A(aA, 0);
    LOAD_A(aB, 1);
    __syncthreads();

    // main loop: one barrier per 64-k. Per iter: compute S (aA) and S+1 (aB);
    // stage chunks S+2,S+3; prefetch A(S+2)->aA, A(S+3)->aB; vmcnt(8) retires
    // exactly the 4 B-stage writes (8 A-loads stay in flight ~1 iter); barrier.
#pragma unroll 1
    for (int S = 0; S < NSTEP; S += 2) {
        COMPUTE(S,     aA, (S) & 3);
        COMPUTE(S + 1, aB, (S + 1) & 3);
        if (S + 2 < NSTEP) {
            STAGE_B(S + 2, (S + 2) & 3);
            STAGE_B(S + 3, (S + 3) & 3);
            LOAD_A(aA, S + 2);
            LOAD_A(aB, S + 3);
            asm volatile("s_waitcnt vmcnt(8)" ::: "memory");
        }
        __builtin_amdgcn_s_barrier();
        asm volatile("" ::: "memory");
    }
#undef STAGE_B
#undef LOAD_A
#undef COMPUTE

    // per-pre-row stats: reduce over the 4 fq lanes sharing a row (same wave)
#pragma unroll
    for (int m = 0; m < 2; ++m) {
        ssr[m] += __shfl_xor(ssr[m], 16); ssr[m] += __shfl_xor(ssr[m], 32);
        zr[m]  += __shfl_xor(zr[m], 16);  zr[m]  += __shfl_xor(zr[m], 32);
        if (fq == 0) {
            const int r  = wv * 32 + m * 16 + fr;
            const int rg = row0 + r;
            rn_s[r] = sqrtf(ssr[m]);
            float sc;
            if (rg < NVL_) sc = score[rg];
            else { float z = zr[m] + bu; sc = 1.f / (1.f + expf(-z)); }
            rsc_s[r] = sc;
        }
    }

    // epilogue: per-query online reductions over this block's TM pre-rows
    // (rn_s/rsc_s own-wave-written; lab_s/qn_sh/qsc_sh published by prologue barrier)
#pragma unroll
    for (int n = 0; n < 8; ++n) {
        const int   c   = n * 16 + fr;
        const float qn  = qn_sh[c];
        const float qsc = qsc_sh[c];
        float mn = INFINITY, mx = -INFINITY, sss = 0.f, ssl = 0.f, s0 = 0.f, cnt = 0.f;
#pragma unroll
        for (int m = 0; m < 2; ++m) {
#pragma unroll
            for (int j = 0; j < 4; ++j) {
                const int r  = wv * 32 + m * 16 + fq * 4 + j;   // C row = pre row
                const int rg = row0 + r;
                const float d    = acc[m][n][j];
                const float cosv = d / fmaxf(rn_s[r] * qn, EPS_);
                float dd = rsc_s[r] - qsc; dd *= dd;
                const float sim   = cosv * (1.f - dd);
                const bool  sel   = (cosv >= THR_);
                const float sim_m = sel ? sim : -1.f;
                const bool  valid = (rg < NCOL_);
                mn = fminf(mn, valid ? sim_m : INFINITY);
                mx = fmaxf(mx, valid ? sim_m : -INFINITY);
                sss += sim_m + 1.f;                 // OOB rows: cos=0 -> exactly 0
                ssl += (sim_m + 1.f) * lab_s[r];
                if (sel) { s0 += sim; cnt += 1.f; }
            }
        }
        mn  = fminf(mn, __shfl_xor(mn, 16)); mn  = fminf(mn, __shfl_xor(mn, 32));
        mx  = fmaxf(mx, __shfl_xor(mx, 16)); mx  = fmaxf(mx, __shfl_xor(mx, 32));
        sss += __shfl_xor(sss, 16); sss += __shfl_xor(sss, 32);
        ssl += __shfl_xor(ssl, 16); ssl += __shfl_xor(ssl, 32);
        s0  += __shfl_xor(s0, 16);  s0  += __shfl_xor(s0, 32);
        cnt += __shfl_xor(cnt, 16); cnt += __shfl_xor(cnt, 32);
        if (fq == 0) {
            atomicMinF(&qmn[c], mn);
            atomicMaxF(&qmx[c], mx);
            atomicAdd(&qss[c],  sss);
            atomicAdd(&qssl[c], ssl);
            atomicAdd(&qs0[c],  s0);
            atomicAdd(&qcnt[c], cnt);
        }
    }
    __syncthreads();
    if (t < NQ_) {
        atomicMinF(ws + WS_MN + t, qmn[t]);
        atomicMaxF(ws + WS_MX + t, qmx[t]);
        atomicAdd(ws + WS_SS + t,  qss[t]);
        atomicAdd(ws + WS_SSL + t, qssl[t]);
        atomicAdd(ws + WS_S0 + t,  qs0[t]);
        atomicAdd(ws + WS_CNT + t, qcnt[t]);
    }
}

// ---------------- kernel 3: finalize outputs ----------------
__global__ void lpe_final(float* out, const float* ws) {
    int t = threadIdx.x;
    if (t < BS_) {
        out[t] = 1.f;            // exp_itm_label[:64]
        out[192 + t] = 1.f;      // exp_wo_alter_label[:64]
        out[385 + t] = 0.f;      // weights[:64]
    }
    if (t == 0) out[384] = 1.0f; // gamma = 131264/131264
    if (t >= BS_ && t < NVL_) {
        int i = t - BS_;
        float mn   = ws[WS_MN + i],  mx   = ws[WS_MX + i];
        float ssP  = ws[WS_SS + i],  sslP = ws[WS_SSL + i];
        float s0   = ws[WS_S0 + i],  cnt  = ws[WS_CNT + i];
        float Sl   = ws[WS_SL];
        float denomA = mx - mn + 1e-8f;
        float shift  = mn + 1.f;            // == 0 when min is the -1 sentinel
        float sumd = (ssP - (float)NCOL_ * shift) / denomA;
        float num  = (sslP - shift * Sl) / denomA;
        float wo   = num / (sumd + 1e-8f);
        float alt  = fmaxf(wo, 0.f);
        float w    = (cnt != 0.f) ? s0 / fmaxf(cnt, 1.f) : 0.f;
        float wt   = fmaxf(w - THR_, 0.f) / (1.f - THR_);
        out[BS_ + i] = alt;          // exp_itm_label[64:]
        out[192 + BS_ + i] = wo;     // exp_wo_alter_label[64:]
        out[385 + BS_ + i] = wt;     // weights[64:]
    }
}

extern "C" void kernel_launch(void* const* d_in, const int* in_sizes, int n_in,
                              void* d_out, int out_size, void* d_ws, size_t ws_size,
                              hipStream_t stream) {
    const float* vl    = (const float*)d_in[0];
    const float* score = (const float*)d_in[1];
    const float* itm   = (const float*)d_in[2];
    const float* queue = (const float*)d_in[3];
    const float* expl  = (const float*)d_in[4];
    const float* W     = (const float*)d_in[5];
    const float* b     = (const float*)d_in[6];
    float* out = (float*)d_out;
    float* ws  = (float*)d_ws;

    lpe_init<<<1, 256, 0, stream>>>(ws);
    lpe_prep<<<NQ_ + 256, 256, 0, stream>>>(vl, itm, expl, ws);
    const int nblk = (NCOL_ + TM - 1) / TM;   // 1026
    lpe_main<<<nblk, 256, 0, stream>>>(vl, score, itm, queue, expl, W, b, ws);
    lpe_final<<<1, 256, 0, stream>>>(out, ws);
}